// Round 10
// baseline (36.407 us; speedup 1.0000x reference)
//
#include <hip/hip_runtime.h>

#define NF 39
#define NE 40
#define NB 4096
#define NSLOT 1536            // 6 tiles * 256 G slots per sample
#define NBLK 512
#define SPW 2                 // samples per wave
#define SPB 8                 // samples per block (4 waves * SPW)
#define K2_BLOCKS 48          // 48 * 32 slots = 1536
#define EPS 1.0e-3f

typedef __attribute__((ext_vector_type(8))) short short8;
typedef __attribute__((ext_vector_type(4))) float floatx4;

__device__ __forceinline__ unsigned int f2bf(float f) {
    unsigned int b = __float_as_uint(f);
    b += 0x7FFFu + ((b >> 16) & 1u);   // round-to-nearest-even
    return b >> 16;
}

__device__ __forceinline__ float bf2f(unsigned int u) {
    return __uint_as_float(u << 16);
}

__device__ __forceinline__ short8 pack8(float4 a, float4 b) {
    union { unsigned int u[4]; short8 s; } o;
    o.u[0] = f2bf(a.x) | (f2bf(a.y) << 16);
    o.u[1] = f2bf(a.z) | (f2bf(a.w) << 16);
    o.u[2] = f2bf(b.x) | (f2bf(b.y) << 16);
    o.u[3] = f2bf(b.z) | (f2bf(b.w) << 16);
    return o.s;
}

// Direct-to-register fragment gather for one sample (validated R4-R9).
__device__ __forceinline__ void load_frags(
    const int* __restrict__ ip, const float* __restrict__ v,
    int rbase, int ehalf, short8 F0[3], short8 F1[3])
{
    const float4 zero4 = {0.f, 0.f, 0.f, 0.f};
#pragma unroll
    for (int I = 0; I < 3; ++I) {
        const int r = rbase + 16 * I;
        const bool vr = (r < NF);
        const int id = vr ? ip[r] : 0;
        const float* vrow = v + (size_t)id * NE;
        const float4 a  = vr ? *reinterpret_cast<const float4*>(vrow + ehalf * 8)     : zero4;
        const float4 bq = vr ? *reinterpret_cast<const float4*>(vrow + ehalf * 8 + 4) : zero4;
        F0[I] = pack8(a, bq);
        const bool v1 = vr && (ehalf == 0);
        const float4 c_ = v1 ? *reinterpret_cast<const float4*>(vrow + 32) : zero4;
        const float4 d_ = v1 ? *reinterpret_cast<const float4*>(vrow + 36) : zero4;
        F1[I] = pack8(c_, d_);
    }
}

__device__ __forceinline__ void gram_mfma(const short8 F0[3], const short8 F1[3], floatx4 acc[6])
{
    acc[0] = __builtin_amdgcn_mfma_f32_16x16x32_bf16(F0[0], F0[0], acc[0], 0, 0, 0);
    acc[1] = __builtin_amdgcn_mfma_f32_16x16x32_bf16(F0[0], F0[1], acc[1], 0, 0, 0);
    acc[2] = __builtin_amdgcn_mfma_f32_16x16x32_bf16(F0[0], F0[2], acc[2], 0, 0, 0);
    acc[3] = __builtin_amdgcn_mfma_f32_16x16x32_bf16(F0[1], F0[1], acc[3], 0, 0, 0);
    acc[4] = __builtin_amdgcn_mfma_f32_16x16x32_bf16(F0[1], F0[2], acc[4], 0, 0, 0);
    acc[5] = __builtin_amdgcn_mfma_f32_16x16x32_bf16(F0[2], F0[2], acc[5], 0, 0, 0);
    acc[0] = __builtin_amdgcn_mfma_f32_16x16x32_bf16(F1[0], F1[0], acc[0], 0, 0, 0);
    acc[1] = __builtin_amdgcn_mfma_f32_16x16x32_bf16(F1[0], F1[1], acc[1], 0, 0, 0);
    acc[2] = __builtin_amdgcn_mfma_f32_16x16x32_bf16(F1[0], F1[2], acc[2], 0, 0, 0);
    acc[3] = __builtin_amdgcn_mfma_f32_16x16x32_bf16(F1[1], F1[1], acc[3], 0, 0, 0);
    acc[4] = __builtin_amdgcn_mfma_f32_16x16x32_bf16(F1[1], F1[2], acc[4], 0, 0, 0);
    acc[5] = __builtin_amdgcn_mfma_f32_16x16x32_bf16(F1[2], F1[2], acc[5], 0, 0, 0);
}

// ---------------- Kernel 1: gather + Gram -> bf16 G slots + lsum (no LDS, no barriers) ----------------
__global__ __launch_bounds__(256) void fm_k1(
    const int* __restrict__ inputs, const float* __restrict__ w,
    const float* __restrict__ v, unsigned short* __restrict__ Gb,
    float* __restrict__ lsum)
{
    const int t = threadIdx.x, wid = t >> 6, lane = t & 63;
    const int rbase = lane & 15, ehalf = lane >> 4;
    const int b0 = blockIdx.x * SPB;

#pragma unroll
    for (int s = 0; s < SPW; ++s) {
        const int smp = b0 + wid * SPW + s;
        const int* ip = inputs + (size_t)smp * NF;
        short8 F0[3], F1[3];
        load_frags(ip, v, rbase, ehalf, F0, F1);

        // first-order term
        float wv = (lane < NF) ? w[ip[lane]] : 0.0f;
#pragma unroll
        for (int o = 32; o > 0; o >>= 1) wv += __shfl_down(wv, o, 64);
        if (lane == 0) lsum[smp] = wv;

        floatx4 acc[6] = {};
        gram_mfma(F0, F1, acc);

        // store G as bf16, slot-major: [smp][tile*256 + lane*4 + q] (8B/lane, coalesced)
        unsigned short* gr = Gb + (size_t)smp * NSLOT;
#pragma unroll
        for (int tl = 0; tl < 6; ++tl) {
            uint2 pk;
            pk.x = f2bf(acc[tl][0]) | (f2bf(acc[tl][1]) << 16);
            pk.y = f2bf(acc[tl][2]) | (f2bf(acc[tl][3]) << 16);
            *reinterpret_cast<uint2*>(gr + tl * 256 + lane * 4) = pk;
        }
    }
}

// ---------------- Kernel 2: column stats over bf16 G + mean/scale finalize ----------------
__global__ __launch_bounds__(512) void fm_k2(
    const unsigned short* __restrict__ Gb, const float* __restrict__ ew,
    float* __restrict__ meanArr, float* __restrict__ scaleArr)
{
    const int t = threadIdx.x;
    const int slotL = t & 31, rg = t >> 5;          // 16 row-groups x 256 rows
    const int slot0 = blockIdx.x * 32;
    float s1 = 0.f, s2 = 0.f;
#pragma unroll 8
    for (int r = 0; r < 256; ++r) {
        const int row = rg * 256 + r;
        const float x = bf2f(Gb[(size_t)row * NSLOT + slot0 + slotL]);
        s1 += x;
        s2 = fmaf(x, x, s2);
    }
    __shared__ float r1[16][32], r2[16][32];
    r1[rg][slotL] = s1;
    r2[rg][slotL] = s2;
    __syncthreads();
    if (t < 32) {
        float a = 0.f, b = 0.f;
#pragma unroll
        for (int g = 0; g < 16; ++g) { a += r1[g][t]; b += r2[g][t]; }
        const int slot = slot0 + t;
        const float m   = a * (1.0f / NB);
        const float var = b * (1.0f / NB) - m * m;
        const int tile = slot >> 8;
        const int l    = (slot & 255) >> 2;
        const int q    = slot & 3;
        const int TI[6] = {0, 0, 0, 1, 1, 2};
        const int TJ[6] = {0, 1, 2, 1, 2, 2};
        const int gi = 16 * TI[tile] + ((l >> 4) << 2) + q;
        const int gj = 16 * TJ[tile] + (l & 15);
        float scl = 0.0f;
        if (gi < gj && gj < NF) {
            const int p = 38 * gi - (gi * (gi - 1)) / 2 + (gj - gi - 1);
            scl = ew[p] * rsqrtf(var + EPS);
        }
        meanArr[slot]  = m;
        scaleArr[slot] = scl;
    }
}

// ---------------- Kernel 3: stream bf16 G + normalize-reduce + first-order ----------------
__global__ __launch_bounds__(256) void fm_k3(
    const unsigned short* __restrict__ Gb, const float* __restrict__ lsum,
    const float* __restrict__ meanArr, const float* __restrict__ scaleArr,
    const float* __restrict__ bias, float* __restrict__ out)
{
    const int t = threadIdx.x, wid = t >> 6, lane = t & 63;
    const int b0 = blockIdx.x * SPB;

    floatx4 mf[6], sf[6];
#pragma unroll
    for (int tl = 0; tl < 6; ++tl) {
        mf[tl] = *reinterpret_cast<const floatx4*>(meanArr  + tl * 256 + lane * 4);
        sf[tl] = *reinterpret_cast<const floatx4*>(scaleArr + tl * 256 + lane * 4);
    }
    const float bs = bias[0];

#pragma unroll
    for (int s = 0; s < SPW; ++s) {
        const int smp = b0 + wid * SPW + s;
        const unsigned short* gr = Gb + (size_t)smp * NSLOT;
        float tot = (lane == 0) ? lsum[smp] : 0.0f;
#pragma unroll
        for (int tl = 0; tl < 6; ++tl) {
            const uint2 pk = *reinterpret_cast<const uint2*>(gr + tl * 256 + lane * 4);
            const float g0 = bf2f(pk.x & 0xFFFFu);
            const float g1 = bf2f(pk.x >> 16);
            const float g2 = bf2f(pk.y & 0xFFFFu);
            const float g3 = bf2f(pk.y >> 16);
            tot += (g0 - mf[tl][0]) * sf[tl][0];
            tot += (g1 - mf[tl][1]) * sf[tl][1];
            tot += (g2 - mf[tl][2]) * sf[tl][2];
            tot += (g3 - mf[tl][3]) * sf[tl][3];
        }
#pragma unroll
        for (int o = 32; o > 0; o >>= 1) tot += __shfl_down(tot, o, 64);
        if (lane == 0) out[smp] = tot + bs;
    }
}

extern "C" void kernel_launch(void* const* d_in, const int* in_sizes, int n_in,
                              void* d_out, int out_size, void* d_ws, size_t ws_size,
                              hipStream_t stream)
{
    const int*   inputs = (const int*)  d_in[0];
    // d_in[1]=rows, d_in[2]=cols reproduced in-kernel (validated R2-R9)
    const float* w      = (const float*)d_in[3];
    const float* v      = (const float*)d_in[4];
    const float* bias   = (const float*)d_in[5];
    const float* ew     = (const float*)d_in[6];
    float*       out    = (float*)      d_out;

    // ws: Gb bf16[4096*1536] | floats: lsum[4096] | mean[1536] | scale[1536]
    unsigned short* Gb = (unsigned short*)d_ws;
    float* lsum   = (float*)(Gb + (size_t)NB * NSLOT);
    float* meanA  = lsum + NB;
    float* scaleA = meanA + NSLOT;

    fm_k1<<<NBLK,      256, 0, stream>>>(inputs, w, v, Gb, lsum);
    fm_k2<<<K2_BLOCKS, 512, 0, stream>>>(Gb, ew, meanA, scaleA);
    fm_k3<<<NBLK,      256, 0, stream>>>(Gb, lsum, meanA, scaleA, bias, out);
}

// Round 11
// 30.234 us; speedup vs baseline: 1.2042x; 1.2042x over previous
//
#include <hip/hip_runtime.h>

#define NF 39
#define NE 40
#define NB 4096
#define NSLOT 1536            // 6 tiles * 256 G slots per sample
#define NBLK 512
#define SPW 2                 // samples per wave
#define SPB 8                 // samples per block (4 waves * SPW)
#define K2_BLOCKS 48          // 48 * 32 slots = 1536
#define EPS 1.0e-3f

typedef __attribute__((ext_vector_type(8))) short short8;
typedef __attribute__((ext_vector_type(4))) float floatx4;

__device__ __forceinline__ unsigned int f2bf(float f) {
    unsigned int b = __float_as_uint(f);
    b += 0x7FFFu + ((b >> 16) & 1u);   // round-to-nearest-even
    return b >> 16;
}

__device__ __forceinline__ float bf2f(unsigned int u) {
    return __uint_as_float(u << 16);
}

__device__ __forceinline__ short8 pack8(float4 a, float4 b) {
    union { unsigned int u[4]; short8 s; } o;
    o.u[0] = f2bf(a.x) | (f2bf(a.y) << 16);
    o.u[1] = f2bf(a.z) | (f2bf(a.w) << 16);
    o.u[2] = f2bf(b.x) | (f2bf(b.y) << 16);
    o.u[3] = f2bf(b.z) | (f2bf(b.w) << 16);
    return o.s;
}

// Direct-to-register fragment gather for one sample (validated R4-R10).
__device__ __forceinline__ void load_frags(
    const int* __restrict__ ip, const float* __restrict__ v,
    int rbase, int ehalf, short8 F0[3], short8 F1[3])
{
    const float4 zero4 = {0.f, 0.f, 0.f, 0.f};
#pragma unroll
    for (int I = 0; I < 3; ++I) {
        const int r = rbase + 16 * I;
        const bool vr = (r < NF);
        const int id = vr ? ip[r] : 0;
        const float* vrow = v + (size_t)id * NE;
        const float4 a  = vr ? *reinterpret_cast<const float4*>(vrow + ehalf * 8)     : zero4;
        const float4 bq = vr ? *reinterpret_cast<const float4*>(vrow + ehalf * 8 + 4) : zero4;
        F0[I] = pack8(a, bq);
        const bool v1 = vr && (ehalf == 0);
        const float4 c_ = v1 ? *reinterpret_cast<const float4*>(vrow + 32) : zero4;
        const float4 d_ = v1 ? *reinterpret_cast<const float4*>(vrow + 36) : zero4;
        F1[I] = pack8(c_, d_);
    }
}

__device__ __forceinline__ void gram_mfma(const short8 F0[3], const short8 F1[3], floatx4 acc[6])
{
    acc[0] = __builtin_amdgcn_mfma_f32_16x16x32_bf16(F0[0], F0[0], acc[0], 0, 0, 0);
    acc[1] = __builtin_amdgcn_mfma_f32_16x16x32_bf16(F0[0], F0[1], acc[1], 0, 0, 0);
    acc[2] = __builtin_amdgcn_mfma_f32_16x16x32_bf16(F0[0], F0[2], acc[2], 0, 0, 0);
    acc[3] = __builtin_amdgcn_mfma_f32_16x16x32_bf16(F0[1], F0[1], acc[3], 0, 0, 0);
    acc[4] = __builtin_amdgcn_mfma_f32_16x16x32_bf16(F0[1], F0[2], acc[4], 0, 0, 0);
    acc[5] = __builtin_amdgcn_mfma_f32_16x16x32_bf16(F0[2], F0[2], acc[5], 0, 0, 0);
    acc[0] = __builtin_amdgcn_mfma_f32_16x16x32_bf16(F1[0], F1[0], acc[0], 0, 0, 0);
    acc[1] = __builtin_amdgcn_mfma_f32_16x16x32_bf16(F1[0], F1[1], acc[1], 0, 0, 0);
    acc[2] = __builtin_amdgcn_mfma_f32_16x16x32_bf16(F1[0], F1[2], acc[2], 0, 0, 0);
    acc[3] = __builtin_amdgcn_mfma_f32_16x16x32_bf16(F1[1], F1[1], acc[3], 0, 0, 0);
    acc[4] = __builtin_amdgcn_mfma_f32_16x16x32_bf16(F1[1], F1[2], acc[4], 0, 0, 0);
    acc[5] = __builtin_amdgcn_mfma_f32_16x16x32_bf16(F1[2], F1[2], acc[5], 0, 0, 0);
}

// ---------------- Kernel 1: gather + Gram -> bf16 G + LDS stats fold + lsum ----------------
__global__ __launch_bounds__(256) void fm_k1(
    const int* __restrict__ inputs, const float* __restrict__ w,
    const float* __restrict__ v, unsigned short* __restrict__ Gb,
    float* __restrict__ lsum, float* __restrict__ partial)
{
    __shared__ float red[4 * 2 * NSLOT];   // 48 KB cross-wave stats fold
    const int t = threadIdx.x, wid = t >> 6, lane = t & 63;
    const int rbase = lane & 15, ehalf = lane >> 4;
    const int b0 = blockIdx.x * SPB;

    floatx4 sum[6] = {}, sq[6] = {};
#pragma unroll
    for (int s = 0; s < SPW; ++s) {
        const int smp = b0 + wid * SPW + s;
        const int* ip = inputs + (size_t)smp * NF;
        short8 F0[3], F1[3];
        load_frags(ip, v, rbase, ehalf, F0, F1);

        // first-order term
        float wv = (lane < NF) ? w[ip[lane]] : 0.0f;
#pragma unroll
        for (int o = 32; o > 0; o >>= 1) wv += __shfl_down(wv, o, 64);
        if (lane == 0) lsum[smp] = wv;

        floatx4 acc[6] = {};
        gram_mfma(F0, F1, acc);

        // persist G as bf16, slot-major (8 B/lane coalesced)
        unsigned short* gr = Gb + (size_t)smp * NSLOT;
#pragma unroll
        for (int tl = 0; tl < 6; ++tl) {
            uint2 pk;
            pk.x = f2bf(acc[tl][0]) | (f2bf(acc[tl][1]) << 16);
            pk.y = f2bf(acc[tl][2]) | (f2bf(acc[tl][3]) << 16);
            *reinterpret_cast<uint2*>(gr + tl * 256 + lane * 4) = pk;
            sum[tl] += acc[tl];
            sq[tl]  += acc[tl] * acc[tl];
        }
    }

    float* rw = &red[wid * 2 * NSLOT];
#pragma unroll
    for (int tl = 0; tl < 6; ++tl) {
        *reinterpret_cast<floatx4*>(rw + tl * 256 + lane * 4)         = sum[tl];
        *reinterpret_cast<floatx4*>(rw + NSLOT + tl * 256 + lane * 4) = sq[tl];
    }
    __syncthreads();
    float* po = partial + (size_t)blockIdx.x * (2 * NSLOT);
    for (int j = t; j < 2 * NSLOT; j += 256)
        po[j] = red[j] + red[2 * NSLOT + j] + red[4 * NSLOT + j] + red[6 * NSLOT + j];
}

// ---------------- Kernel 2: fused column-reduce + mean/scale finalize (R6-proven) ----------------
__global__ __launch_bounds__(256) void fm_k2(
    const float* __restrict__ partial, const float* __restrict__ ew,
    float* __restrict__ meanArr, float* __restrict__ scaleArr)
{
    const int t = threadIdx.x;
    const int slotL = t & 31, rg = t >> 5;          // 8 row-groups x 64 rows
    const int slot0 = blockIdx.x * 32;
    float s1 = 0.f, s2 = 0.f;
#pragma unroll 8
    for (int r = 0; r < 64; ++r) {
        const float* row = partial + (size_t)(rg * 64 + r) * (2 * NSLOT);
        s1 += row[slot0 + slotL];
        s2 += row[NSLOT + slot0 + slotL];
    }
    __shared__ float r1[8][32], r2[8][32];
    r1[rg][slotL] = s1;
    r2[rg][slotL] = s2;
    __syncthreads();
    if (t < 32) {
        float a = 0.f, b = 0.f;
#pragma unroll
        for (int g = 0; g < 8; ++g) { a += r1[g][t]; b += r2[g][t]; }
        const int slot = slot0 + t;
        const float m   = a * (1.0f / NB);
        const float var = b * (1.0f / NB) - m * m;
        const int tile = slot >> 8;
        const int l    = (slot & 255) >> 2;
        const int q    = slot & 3;
        const int TI[6] = {0, 0, 0, 1, 1, 2};
        const int TJ[6] = {0, 1, 2, 1, 2, 2};
        const int gi = 16 * TI[tile] + ((l >> 4) << 2) + q;
        const int gj = 16 * TJ[tile] + (l & 15);
        float scl = 0.0f;
        if (gi < gj && gj < NF) {
            const int p = 38 * gi - (gi * (gi - 1)) / 2 + (gj - gi - 1);
            scl = ew[p] * rsqrtf(var + EPS);
        }
        meanArr[slot]  = m;
        scaleArr[slot] = scl;
    }
}

// ---------------- Kernel 3: stream bf16 G + normalize-reduce + first-order ----------------
__global__ __launch_bounds__(256) void fm_k3(
    const unsigned short* __restrict__ Gb, const float* __restrict__ lsum,
    const float* __restrict__ meanArr, const float* __restrict__ scaleArr,
    const float* __restrict__ bias, float* __restrict__ out)
{
    const int t = threadIdx.x, wid = t >> 6, lane = t & 63;
    const int b0 = blockIdx.x * SPB;

    floatx4 mf[6], sf[6];
#pragma unroll
    for (int tl = 0; tl < 6; ++tl) {
        mf[tl] = *reinterpret_cast<const floatx4*>(meanArr  + tl * 256 + lane * 4);
        sf[tl] = *reinterpret_cast<const floatx4*>(scaleArr + tl * 256 + lane * 4);
    }
    const float bs = bias[0];

#pragma unroll
    for (int s = 0; s < SPW; ++s) {
        const int smp = b0 + wid * SPW + s;
        const unsigned short* gr = Gb + (size_t)smp * NSLOT;
        float tot = (lane == 0) ? lsum[smp] : 0.0f;
#pragma unroll
        for (int tl = 0; tl < 6; ++tl) {
            const uint2 pk = *reinterpret_cast<const uint2*>(gr + tl * 256 + lane * 4);
            tot += (bf2f(pk.x & 0xFFFFu) - mf[tl][0]) * sf[tl][0];
            tot += (bf2f(pk.x >> 16)     - mf[tl][1]) * sf[tl][1];
            tot += (bf2f(pk.y & 0xFFFFu) - mf[tl][2]) * sf[tl][2];
            tot += (bf2f(pk.y >> 16)     - mf[tl][3]) * sf[tl][3];
        }
#pragma unroll
        for (int o = 32; o > 0; o >>= 1) tot += __shfl_down(tot, o, 64);
        if (lane == 0) out[smp] = tot + bs;
    }
}

extern "C" void kernel_launch(void* const* d_in, const int* in_sizes, int n_in,
                              void* d_out, int out_size, void* d_ws, size_t ws_size,
                              hipStream_t stream)
{
    const int*   inputs = (const int*)  d_in[0];
    // d_in[1]=rows, d_in[2]=cols reproduced in-kernel (validated R2-R10)
    const float* w      = (const float*)d_in[3];
    const float* v      = (const float*)d_in[4];
    const float* bias   = (const float*)d_in[5];
    const float* ew     = (const float*)d_in[6];
    float*       out    = (float*)      d_out;

    // ws: Gb bf16[4096*1536] | floats: partial[512*3072] | mean[1536] | scale[1536] | lsum[4096]
    unsigned short* Gb = (unsigned short*)d_ws;
    float* partial = (float*)(Gb + (size_t)NB * NSLOT);
    float* meanA   = partial + (size_t)NBLK * 2 * NSLOT;
    float* scaleA  = meanA + NSLOT;
    float* lsum    = scaleA + NSLOT;

    fm_k1<<<NBLK,      256, 0, stream>>>(inputs, w, v, Gb, lsum, partial);
    fm_k2<<<K2_BLOCKS, 256, 0, stream>>>(partial, ew, meanA, scaleA);
    fm_k3<<<NBLK,      256, 0, stream>>>(Gb, lsum, meanA, scaleA, bias, out);
}

// Round 12
// 27.825 us; speedup vs baseline: 1.3084x; 1.0866x over previous
//
#include <hip/hip_runtime.h>

#define NF 39
#define NE 40
#define NB 4096
#define NSLOT 1536            // 6 tiles * 256 G slots per sample
#define NBLK 512
#define SPW 2                 // samples per wave
#define SPB 8                 // samples per block (4 waves * SPW)
#define K2_BLOCKS 48          // 48 * 32 slots = 1536
#define EPS 1.0e-3f

typedef __attribute__((ext_vector_type(8))) short short8;
typedef __attribute__((ext_vector_type(4))) float floatx4;

__device__ __forceinline__ unsigned int f2bf(float f) {
    unsigned int b = __float_as_uint(f);
    b += 0x7FFFu + ((b >> 16) & 1u);   // round-to-nearest-even
    return b >> 16;
}

__device__ __forceinline__ float bf2f(unsigned int u) {
    return __uint_as_float(u << 16);
}

__device__ __forceinline__ short8 pack8(float4 a, float4 b) {
    union { unsigned int u[4]; short8 s; } o;
    o.u[0] = f2bf(a.x) | (f2bf(a.y) << 16);
    o.u[1] = f2bf(a.z) | (f2bf(a.w) << 16);
    o.u[2] = f2bf(b.x) | (f2bf(b.y) << 16);
    o.u[3] = f2bf(b.z) | (f2bf(b.w) << 16);
    return o.s;
}

// Direct-to-register fragment gather for one sample (validated R4-R11).
__device__ __forceinline__ void load_frags(
    const int* __restrict__ ip, const float* __restrict__ v,
    int rbase, int ehalf, short8 F0[3], short8 F1[3])
{
    const float4 zero4 = {0.f, 0.f, 0.f, 0.f};
#pragma unroll
    for (int I = 0; I < 3; ++I) {
        const int r = rbase + 16 * I;
        const bool vr = (r < NF);
        const int id = vr ? ip[r] : 0;
        const float* vrow = v + (size_t)id * NE;
        const float4 a  = vr ? *reinterpret_cast<const float4*>(vrow + ehalf * 8)     : zero4;
        const float4 bq = vr ? *reinterpret_cast<const float4*>(vrow + ehalf * 8 + 4) : zero4;
        F0[I] = pack8(a, bq);
        const bool v1 = vr && (ehalf == 0);
        const float4 c_ = v1 ? *reinterpret_cast<const float4*>(vrow + 32) : zero4;
        const float4 d_ = v1 ? *reinterpret_cast<const float4*>(vrow + 36) : zero4;
        F1[I] = pack8(c_, d_);
    }
}

__device__ __forceinline__ void gram_mfma(const short8 F0[3], const short8 F1[3], floatx4 acc[6])
{
    acc[0] = __builtin_amdgcn_mfma_f32_16x16x32_bf16(F0[0], F0[0], acc[0], 0, 0, 0);
    acc[1] = __builtin_amdgcn_mfma_f32_16x16x32_bf16(F0[0], F0[1], acc[1], 0, 0, 0);
    acc[2] = __builtin_amdgcn_mfma_f32_16x16x32_bf16(F0[0], F0[2], acc[2], 0, 0, 0);
    acc[3] = __builtin_amdgcn_mfma_f32_16x16x32_bf16(F0[1], F0[1], acc[3], 0, 0, 0);
    acc[4] = __builtin_amdgcn_mfma_f32_16x16x32_bf16(F0[1], F0[2], acc[4], 0, 0, 0);
    acc[5] = __builtin_amdgcn_mfma_f32_16x16x32_bf16(F0[2], F0[2], acc[5], 0, 0, 0);
    acc[0] = __builtin_amdgcn_mfma_f32_16x16x32_bf16(F1[0], F1[0], acc[0], 0, 0, 0);
    acc[1] = __builtin_amdgcn_mfma_f32_16x16x32_bf16(F1[0], F1[1], acc[1], 0, 0, 0);
    acc[2] = __builtin_amdgcn_mfma_f32_16x16x32_bf16(F1[0], F1[2], acc[2], 0, 0, 0);
    acc[3] = __builtin_amdgcn_mfma_f32_16x16x32_bf16(F1[1], F1[1], acc[3], 0, 0, 0);
    acc[4] = __builtin_amdgcn_mfma_f32_16x16x32_bf16(F1[1], F1[2], acc[4], 0, 0, 0);
    acc[5] = __builtin_amdgcn_mfma_f32_16x16x32_bf16(F1[2], F1[2], acc[5], 0, 0, 0);
}

// ---------------- Kernel 1: gather + Gram -> bf16 G + LDS stats fold + bf16 partial + lsum ----------------
__global__ __launch_bounds__(256) void fm_k1(
    const int* __restrict__ inputs, const float* __restrict__ w,
    const float* __restrict__ v, unsigned short* __restrict__ Gb,
    float* __restrict__ lsum, unsigned int* __restrict__ partial)
{
    __shared__ float red[4 * 2 * NSLOT];   // 48 KB cross-wave stats fold
    const int t = threadIdx.x, wid = t >> 6, lane = t & 63;
    const int rbase = lane & 15, ehalf = lane >> 4;
    const int b0 = blockIdx.x * SPB;

    floatx4 sum[6] = {}, sq[6] = {};
#pragma unroll
    for (int s = 0; s < SPW; ++s) {
        const int smp = b0 + wid * SPW + s;
        const int* ip = inputs + (size_t)smp * NF;
        short8 F0[3], F1[3];
        load_frags(ip, v, rbase, ehalf, F0, F1);

        // first-order term
        float wv = (lane < NF) ? w[ip[lane]] : 0.0f;
#pragma unroll
        for (int o = 32; o > 0; o >>= 1) wv += __shfl_down(wv, o, 64);
        if (lane == 0) lsum[smp] = wv;

        floatx4 acc[6] = {};
        gram_mfma(F0, F1, acc);

        // persist G as bf16, slot-major (8 B/lane coalesced)
        unsigned short* gr = Gb + (size_t)smp * NSLOT;
#pragma unroll
        for (int tl = 0; tl < 6; ++tl) {
            uint2 pk;
            pk.x = f2bf(acc[tl][0]) | (f2bf(acc[tl][1]) << 16);
            pk.y = f2bf(acc[tl][2]) | (f2bf(acc[tl][3]) << 16);
            *reinterpret_cast<uint2*>(gr + tl * 256 + lane * 4) = pk;
            sum[tl] += acc[tl];
            sq[tl]  += acc[tl] * acc[tl];
        }
    }

    float* rw = &red[wid * 2 * NSLOT];
#pragma unroll
    for (int tl = 0; tl < 6; ++tl) {
        *reinterpret_cast<floatx4*>(rw + tl * 256 + lane * 4)         = sum[tl];
        *reinterpret_cast<floatx4*>(rw + NSLOT + tl * 256 + lane * 4) = sq[tl];
    }
    __syncthreads();
    // pack per-slot (sum, sumsq) into one u32: sum in HIGH half, sq in LOW half
    unsigned int* po = partial + (size_t)blockIdx.x * NSLOT;
    for (int j = t; j < NSLOT; j += 256) {
        const float s = red[j] + red[2 * NSLOT + j] + red[4 * NSLOT + j] + red[6 * NSLOT + j];
        const float q = red[NSLOT + j] + red[3 * NSLOT + j] + red[5 * NSLOT + j] + red[7 * NSLOT + j];
        po[j] = (f2bf(s) << 16) | f2bf(q);
    }
}

// ---------------- Kernel 2: fused column-reduce + mean/scale finalize (bf16 partials) ----------------
__global__ __launch_bounds__(256) void fm_k2(
    const unsigned int* __restrict__ partial, const float* __restrict__ ew,
    float* __restrict__ meanArr, float* __restrict__ scaleArr)
{
    const int t = threadIdx.x;
    const int slotL = t & 31, rg = t >> 5;          // 8 row-groups x 64 rows
    const int slot0 = blockIdx.x * 32;
    float s1 = 0.f, s2 = 0.f;
#pragma unroll 8
    for (int r = 0; r < 64; ++r) {
        const unsigned int u = partial[(size_t)(rg * 64 + r) * NSLOT + slot0 + slotL];
        s1 += __uint_as_float(u & 0xFFFF0000u);   // sum (high half)
        s2 += __uint_as_float(u << 16);           // sumsq (low half)
    }
    __shared__ float r1[8][32], r2[8][32];
    r1[rg][slotL] = s1;
    r2[rg][slotL] = s2;
    __syncthreads();
    if (t < 32) {
        float a = 0.f, b = 0.f;
#pragma unroll
        for (int g = 0; g < 8; ++g) { a += r1[g][t]; b += r2[g][t]; }
        const int slot = slot0 + t;
        const float m   = a * (1.0f / NB);
        const float var = b * (1.0f / NB) - m * m;
        const int tile = slot >> 8;
        const int l    = (slot & 255) >> 2;
        const int q    = slot & 3;
        const int TI[6] = {0, 0, 0, 1, 1, 2};
        const int TJ[6] = {0, 1, 2, 1, 2, 2};
        const int gi = 16 * TI[tile] + ((l >> 4) << 2) + q;
        const int gj = 16 * TJ[tile] + (l & 15);
        float scl = 0.0f;
        if (gi < gj && gj < NF) {
            const int p = 38 * gi - (gi * (gi - 1)) / 2 + (gj - gi - 1);
            scl = ew[p] * rsqrtf(var + EPS);
        }
        meanArr[slot]  = m;
        scaleArr[slot] = scl;
    }
}

// ---------------- Kernel 3: stream bf16 G + normalize-reduce + first-order ----------------
__global__ __launch_bounds__(256) void fm_k3(
    const unsigned short* __restrict__ Gb, const float* __restrict__ lsum,
    const float* __restrict__ meanArr, const float* __restrict__ scaleArr,
    const float* __restrict__ bias, float* __restrict__ out)
{
    const int t = threadIdx.x, wid = t >> 6, lane = t & 63;
    const int b0 = blockIdx.x * SPB;

    floatx4 mf[6], sf[6];
#pragma unroll
    for (int tl = 0; tl < 6; ++tl) {
        mf[tl] = *reinterpret_cast<const floatx4*>(meanArr  + tl * 256 + lane * 4);
        sf[tl] = *reinterpret_cast<const floatx4*>(scaleArr + tl * 256 + lane * 4);
    }
    const float bs = bias[0];

#pragma unroll
    for (int s = 0; s < SPW; ++s) {
        const int smp = b0 + wid * SPW + s;
        const unsigned short* gr = Gb + (size_t)smp * NSLOT;
        float tot = (lane == 0) ? lsum[smp] : 0.0f;
#pragma unroll
        for (int tl = 0; tl < 6; ++tl) {
            const uint2 pk = *reinterpret_cast<const uint2*>(gr + tl * 256 + lane * 4);
            tot += (bf2f(pk.x & 0xFFFFu) - mf[tl][0]) * sf[tl][0];
            tot += (bf2f(pk.x >> 16)     - mf[tl][1]) * sf[tl][1];
            tot += (bf2f(pk.y & 0xFFFFu) - mf[tl][2]) * sf[tl][2];
            tot += (bf2f(pk.y >> 16)     - mf[tl][3]) * sf[tl][3];
        }
#pragma unroll
        for (int o = 32; o > 0; o >>= 1) tot += __shfl_down(tot, o, 64);
        if (lane == 0) out[smp] = tot + bs;
    }
}

extern "C" void kernel_launch(void* const* d_in, const int* in_sizes, int n_in,
                              void* d_out, int out_size, void* d_ws, size_t ws_size,
                              hipStream_t stream)
{
    const int*   inputs = (const int*)  d_in[0];
    // d_in[1]=rows, d_in[2]=cols reproduced in-kernel (validated R2-R11)
    const float* w      = (const float*)d_in[3];
    const float* v      = (const float*)d_in[4];
    const float* bias   = (const float*)d_in[5];
    const float* ew     = (const float*)d_in[6];
    float*       out    = (float*)      d_out;

    // ws: Gb bf16[4096*1536] | partial u32[512*1536] | floats: mean[1536] | scale[1536] | lsum[4096]
    unsigned short* Gb = (unsigned short*)d_ws;
    unsigned int* partial = (unsigned int*)(Gb + (size_t)NB * NSLOT);
    float* meanA   = (float*)(partial + (size_t)NBLK * NSLOT);
    float* scaleA  = meanA + NSLOT;
    float* lsum    = scaleA + NSLOT;

    fm_k1<<<NBLK,      256, 0, stream>>>(inputs, w, v, Gb, lsum, partial);
    fm_k2<<<K2_BLOCKS, 256, 0, stream>>>(partial, ew, meanA, scaleA);
    fm_k3<<<NBLK,      256, 0, stream>>>(Gb, lsum, meanA, scaleA, bias, out);
}